// Round 1
// baseline (9069.902 us; speedup 1.0000x reference)
//
#include <hip/hip_runtime.h>
#include <math.h>

#define KNB 24

// ---------------------------------------------------------------- utilities
__global__ void k_zero(double* acc) {
    if (threadIdx.x < 8) acc[threadIdx.x] = 0.0;
}

// x [B,C,N] -> feats [B,N,C]
__global__ void k_transpose(const float* __restrict__ x, float* __restrict__ feats,
                            int B, int C, int N) {
    int idx = blockIdx.x * blockDim.x + threadIdx.x;
    int tot = B * C * N;
    if (idx >= tot) return;
    int n = idx % N; int t = idx / N; int c = t % C; int b = t / C;
    feats[((size_t)b * N + n) * C + c] = x[idx];
}

// ---------------------------------------------------------------- FPS
// one workgroup per batch; xyz staged in LDS; dist in registers
__global__ __launch_bounds__(1024) void k_fps(const float* __restrict__ xyz,
                                              int* __restrict__ fi,
                                              int B, int N, int M) {
#pragma clang fp contract(off)
    int b = blockIdx.x;
    int tid = threadIdx.x, bs = blockDim.x;
    extern __shared__ float lds[];
    float* px = lds; float* py = lds + N; float* pz = lds + 2 * N;
    float* rval = lds + 3 * N;           // 32 floats
    int*   ridx = (int*)(rval + 32);     // 33 ints (slot 32 = broadcast)
    const float* p = xyz + (size_t)b * N * 3;
    for (int i = tid; i < N; i += bs) { px[i] = p[i*3]; py[i] = p[i*3+1]; pz[i] = p[i*3+2]; }
    float dist[4];
    int npt = (N + bs - 1) / bs;
    for (int j = 0; j < npt; ++j) dist[j] = 1e10f;
    __syncthreads();
    int far = 0;
    for (int it = 0; it < M; ++it) {
        if (tid == 0) fi[b * M + it] = far;   // scan records carry BEFORE update
        float cx = px[far], cy = py[far], cz = pz[far];
        float bv = -1.0f; int bi = N;
        for (int j = 0; j < npt; ++j) {
            int pi = tid + j * bs;
            if (pi < N) {
                float dx = px[pi] - cx, dy = py[pi] - cy, dz = pz[pi] - cz;
                float d = (dx*dx + dy*dy) + dz*dz;   // ((d0+d1)+d2), no fma
                float dd = fminf(dist[j], d);
                dist[j] = dd;
                if (dd > bv) { bv = dd; bi = pi; }   // pi increasing -> first-max kept
            }
        }
        for (int off = 32; off > 0; off >>= 1) {
            float ov = __shfl_down(bv, off);
            int   oi = __shfl_down(bi, off);
            if (ov > bv || (ov == bv && oi < bi)) { bv = ov; bi = oi; }
        }
        int wid = tid >> 6;
        if ((tid & 63) == 0) { rval[wid] = bv; ridx[wid] = bi; }
        __syncthreads();
        if (tid == 0) {
            int nw = bs >> 6;
            float v = rval[0]; int ii = ridx[0];
            for (int w = 1; w < nw; ++w) {
                float v2 = rval[w]; int i2 = ridx[w];
                if (v2 > v || (v2 == v && i2 < ii)) { v = v2; ii = i2; }
            }
            ridx[32] = ii;
        }
        __syncthreads();
        far = ridx[32];
    }
}

// ---------------------------------------------------------------- gather centers
__global__ void k_gather(const float* __restrict__ xyz, const float* __restrict__ feats,
                         const int* __restrict__ fi, float* __restrict__ lc_xyz,
                         float* __restrict__ lc_x, int B, int N, int G, int C) {
    int i = blockIdx.x * blockDim.x + threadIdx.x;
    int tot = B * G * (C + 3);
    if (i >= tot) return;
    int c = i % (C + 3); int bg = i / (C + 3);
    int b = bg / G;
    int idx = fi[bg];
    if (c < 3) lc_xyz[(size_t)bg * 3 + c] = xyz[((size_t)b * N + idx) * 3 + c];
    else       lc_x[(size_t)bg * C + (c - 3)] = feats[((size_t)b * N + idx) * C + (c - 3)];
}

// ---------------------------------------------------------------- kNN (24 smallest, ties->lower idx)
__global__ __launch_bounds__(256) void k_knn(const float* __restrict__ xyz,
                                             const float* __restrict__ lc_xyz,
                                             int* __restrict__ ki, int B, int N, int G) {
#pragma clang fp contract(off)
    int bg = blockIdx.x; int b = bg / G;
    extern __shared__ float sd[];
    float* rv = sd + N; int* ri = (int*)(rv + 8);
    const float* p = xyz + (size_t)b * N * 3;
    float cx = lc_xyz[(size_t)bg*3], cy = lc_xyz[(size_t)bg*3+1], cz = lc_xyz[(size_t)bg*3+2];
    float cc = (cx*cx + cy*cy) + cz*cz;
    for (int i = threadIdx.x; i < N; i += blockDim.x) {
        float x0 = p[i*3], x1 = p[i*3+1], x2 = p[i*3+2];
        float xx = (x0*x0 + x1*x1) + x2*x2;
        float dt = (cx*x0 + cy*x1) + cz*x2;
        sd[i] = (cc - 2.0f*dt) + xx;          // (cc - 2dot) + xx, matches ref assoc
    }
    __syncthreads();
    for (int kk = 0; kk < KNB; ++kk) {
        float bv = 1e30f; int bi = N;
        for (int i = threadIdx.x; i < N; i += blockDim.x) {
            float v = sd[i];
            if (v < bv) { bv = v; bi = i; }   // i increasing -> first-min kept
        }
        for (int off = 32; off > 0; off >>= 1) {
            float ov = __shfl_down(bv, off); int oi = __shfl_down(bi, off);
            if (ov < bv || (ov == bv && oi < bi)) { bv = ov; bi = oi; }
        }
        int wid = threadIdx.x >> 6;
        if ((threadIdx.x & 63) == 0) { rv[wid] = bv; ri[wid] = bi; }
        __syncthreads();
        if (threadIdx.x == 0) {
            int nw = blockDim.x >> 6;
            float v = rv[0]; int ii = ri[0];
            for (int w = 1; w < nw; ++w) {
                if (rv[w] < v || (rv[w] == v && ri[w] < ii)) { v = rv[w]; ii = ri[w]; }
            }
            ki[(size_t)bg * KNB + kk] = ii;
            sd[ii] = 1e30f;
        }
        __syncthreads();
    }
}

// ---------------------------------------------------------------- global std reduction (sum, sumsq)
__global__ void k_stdsum(const float* __restrict__ feats, const float* __restrict__ lc,
                         const int* __restrict__ ki, double* __restrict__ acc,
                         int B, int N, int G, int C) {
    size_t tot = (size_t)B * G * KNB * C;
    double s = 0.0, s2 = 0.0;
    size_t stride = (size_t)gridDim.x * blockDim.x;
    for (size_t i = (size_t)blockIdx.x * blockDim.x + threadIdx.x; i < tot; i += stride) {
        int c = (int)(i % C); size_t t = i / C; int k = (int)(t % KNB); size_t bg = t / KNB;
        int b = (int)(bg / G);
        int idx = ki[bg * KNB + k];
        float d = feats[((size_t)b * N + idx) * C + c] - lc[bg * C + c];
        s += (double)d; s2 += (double)d * (double)d;
    }
    for (int off = 32; off > 0; off >>= 1) { s += __shfl_down(s, off); s2 += __shfl_down(s2, off); }
    if ((threadIdx.x & 63) == 0) { atomicAdd(acc, s); atomicAdd(acc + 1, s2); }
}

__global__ void k_finalize(const double* __restrict__ acc, float* __restrict__ inv,
                           double nx, double nz) {
    if (threadIdx.x == 0) {
        double vx = (acc[1] - acc[0] * acc[0] / nx) / (nx - 1.0);
        float sx = sqrtf((float)vx);
        inv[0] = 1.0f / (sx + 1e-5f);
        double vz = (acc[3] - acc[2] * acc[2] / nz) / (nz - 1.0);
        float sz = sqrtf((float)vz);
        inv[1] = 1.0f / (sz + 1e-5f);
    }
}

// ---------------------------------------------------------------- LGA feature + pool (one wg per (b,g))
__global__ __launch_bounds__(256) void k_feature(
    const float* __restrict__ xyz, const float* __restrict__ feats,
    const float* __restrict__ lc_xyz, const float* __restrict__ lc_x,
    const int* __restrict__ ki, const float* __restrict__ Bmat,
    const float* __restrict__ inv, float* __restrict__ pooled,
    int B, int N, int G, int C)
{
    int bg = blockIdx.x; int b = bg / G; int g = bg % G;
    int tid = threadIdx.x;
    int C2 = C >> 1;
    int Cout = 2 * C;
    int F = C / 3;                         // tr_embed F = (2C)/(2*3)
    extern __shared__ float sm[];
    float* t7    = sm;                     // [24][7]
    float* sxyzn = t7 + KNB * 7;           // [24][3]
    int*   kidx  = (int*)(sxyzn + KNB * 3);// [24]
    float* semb  = (float*)(kidx + KNB);   // [24][C]

    float invx = inv[0], invz = inv[1];
    float l0 = lc_xyz[(size_t)bg*3], l1 = lc_xyz[(size_t)bg*3+1], l2 = lc_xyz[(size_t)bg*3+2];

    if (tid < KNB) {
        int idx = ki[(size_t)bg * KNB + tid];
        kidx[tid] = idx;
        const float* q = xyz + ((size_t)b * N + idx) * 3;
        float a0 = (q[0]-l0)*invz, a1 = (q[1]-l1)*invz, a2 = (q[2]-l2)*invz;
        float c0 = a1*l2 - a2*l1;          // cross(normed knn_xyz, raw lc_xyz)
        float c1 = a2*l0 - a0*l2;
        float c2 = a0*l1 - a1*l0;
        float dt = (a0*l0 + a1*l1) + a2*l2;
        float* tp = t7 + tid * 7;
        tp[0]=a0; tp[1]=a1; tp[2]=a2; tp[3]=c0; tp[4]=c1; tp[5]=c2; tp[6]=dt;
        sxyzn[tid*3]=a0; sxyzn[tid*3+1]=a1; sxyzn[tid*3+2]=a2;
    }
    __syncthreads();
    const float TWO_PI = 6.2831854820251465f;
    // fourier embedding: emb[k][c] = sin(proj)^5 / cos(proj)^5
    for (int i = tid; i < KNB * C2; i += blockDim.x) {
        int k = i / C2, m2 = i % C2;
        const float* tp = t7 + k * 7;
        float s = 0.0f;
        for (int j = 0; j < 7; ++j) s += tp[j] * Bmat[j * C2 + m2];
        float pr = TWO_PI * s;
        float sn = sinf(pr), cs = cosf(pr);
        float sn2 = sn*sn, cs2 = cs*cs;
        semb[k*C + m2]      = sn2*sn2*sn;
        semb[k*C + C2 + m2] = cs2*cs2*cs;
    }
    __syncthreads();
    // per output channel m: w = (knn_x_w + pe)*pe ; pooled = 2*mean_K(w)  (k_anp cancels)
    for (int m = tid; m < Cout; m += blockDim.x) {
        int c3 = m / (2 * F);
        int r  = m % (2 * F);
        int f  = r >> 1;
        int trig = r & 1;
        float de = powf(100.0f, (float)f / (float)F);
        float lv = (c3 == 0) ? l0 : ((c3 == 1) ? l1 : l2);
        float a2v = (1000.0f * lv) / de;
        float pe2 = trig ? cosf(a2v) : sinf(a2v);
        float lfm = (m < C) ? lc_x[(size_t)bg * C + m] : 0.0f;
        float acc = 0.0f;
        for (int k = 0; k < KNB; ++k) {
            float v;
            if (m < C) {
                v = (feats[((size_t)b * N + kidx[k]) * C + m] - lfm) * invx;
            } else {
                v = semb[k * C + (m - C)];
            }
            float a1v = (1000.0f * sxyzn[k*3 + c3]) / de;
            float pe1 = trig ? cosf(a1v) : sinf(a1v);
            float pe = pe1 + pe2;
            acc += (v + pe) * pe;
        }
        float mean = acc / 24.0f;
        pooled[((size_t)b * Cout + m) * G + g] = 2.0f * mean;   // k_anp + mean = 2*mean
    }
}

// ---------------------------------------------------------------- BatchNorm stats (train mode, biased var)
__global__ __launch_bounds__(256) void k_bnstats(const float* __restrict__ pooled,
                                                 float* __restrict__ stats,
                                                 int B, int Cout, int G) {
    int m = blockIdx.x;
    double s = 0.0, s2 = 0.0;
    for (int i = threadIdx.x; i < B * G; i += blockDim.x) {
        int b = i / G, g = i % G;
        float v = pooled[((size_t)b * Cout + m) * G + g];
        s += (double)v; s2 += (double)v * (double)v;
    }
    for (int off = 32; off > 0; off >>= 1) { s += __shfl_down(s, off); s2 += __shfl_down(s2, off); }
    __shared__ double sw[8], sw2[8];
    int wid = threadIdx.x >> 6;
    if ((threadIdx.x & 63) == 0) { sw[wid] = s; sw2[wid] = s2; }
    __syncthreads();
    if (threadIdx.x == 0) {
        int nw = blockDim.x >> 6;
        double ts = 0.0, ts2 = 0.0;
        for (int w = 0; w < nw; ++w) { ts += sw[w]; ts2 += sw2[w]; }
        double n = (double)(B * G);
        double mean = ts / n;
        double var = ts2 / n - mean * mean;
        stats[2*m]   = (float)mean;
        stats[2*m+1] = (float)var;
    }
}

// BN apply + exact GELU; transposed=1 writes [B,G,Cout] (feats layout for next stage)
__global__ void k_bn_gelu(const float* __restrict__ pooled, const float* __restrict__ stats,
                          const float* __restrict__ gamma, const float* __restrict__ beta,
                          float* __restrict__ out, int B, int Cout, int G, int transposed) {
    int i = blockIdx.x * blockDim.x + threadIdx.x;
    int tot = B * Cout * G;
    if (i >= tot) return;
    int g = i % G; int t = i / G; int m = t % Cout; int b = t / Cout;
    float v = pooled[i];
    float mean = stats[2*m], var = stats[2*m+1];
    float y = (v - mean) / sqrtf(var + 1e-5f) * gamma[m] + beta[m];
    float ge = 0.5f * y * (1.0f + erff(y / 1.4142135381698608f));
    if (transposed) out[((size_t)b * G + g) * Cout + m] = ge;
    else            out[i] = ge;
}

// ---------------------------------------------------------------- launch
extern "C" void kernel_launch(void* const* d_in, const int* in_sizes, int n_in,
                              void* d_out, int out_size, void* d_ws, size_t ws_size,
                              hipStream_t stream) {
    const int B = 4, N1 = 4096, C0 = 72, G1 = 2048, Co1 = 144;
    const int N2 = 2048, C1 = 144, G2 = 1024, Co2 = 288;

    const float* xyz = (const float*)d_in[0];
    const float* x0  = (const float*)d_in[1];
    const float* B0  = (const float*)d_in[2];
    const float* B1  = (const float*)d_in[3];
    const float* g0  = (const float*)d_in[4];
    const float* be0 = (const float*)d_in[5];
    const float* g1  = (const float*)d_in[6];
    const float* be1 = (const float*)d_in[7];
    float* out = (float*)d_out;

    char* wp = (char*)d_ws;
    size_t off = 0;
    auto A = [&](size_t bytes) -> void* {
        void* p = wp + off;
        off += (bytes + 255) & ~(size_t)255;
        return p;
    };
    float* feats1  = (float*)A((size_t)B*N1*C0*4);
    int*   fi1     = (int*)  A((size_t)B*G1*4);
    float* lcx1    = (float*)A((size_t)B*G1*3*4);
    float* lcf1    = (float*)A((size_t)B*G1*C0*4);
    int*   ki1     = (int*)  A((size_t)B*G1*KNB*4);
    double* acc    = (double*)A(8*8);
    float* inv1    = (float*)A(2*4);
    float* inv2    = (float*)A(2*4);
    float* pooled1 = (float*)A((size_t)B*Co1*G1*4);
    float* stats1  = (float*)A((size_t)Co1*2*4);
    float* feats2  = (float*)A((size_t)B*N2*C1*4);
    float* lcx2    = (float*)A((size_t)B*G2*3*4);
    float* stats2  = (float*)A((size_t)Co2*2*4);
    // aliases (lifetimes disjoint, sizes checked: equal or smaller)
    int*   fi2     = fi1;
    float* lcf2    = lcf1;     // B*G2*C1 == B*G1*C0
    int*   ki2     = ki1;
    float* pooled2 = feats1;   // B*Co2*G2 == B*N1*C0

    k_zero<<<1, 64, 0, stream>>>(acc);
    k_transpose<<<(B*C0*N1 + 255)/256, 256, 0, stream>>>(x0, feats1, B, C0, N1);

    // ---- stage 1 ----
    k_fps<<<B, 1024, (size_t)(3*N1 + 80)*4, stream>>>(xyz, fi1, B, N1, G1);
    k_gather<<<(B*G1*(C0+3) + 255)/256, 256, 0, stream>>>(xyz, feats1, fi1, lcx1, lcf1, B, N1, G1, C0);
    k_knn<<<B*G1, 256, (size_t)(N1 + 32)*4, stream>>>(xyz, lcx1, ki1, B, N1, G1);
    k_stdsum<<<512, 256, 0, stream>>>(feats1, lcf1, ki1, acc,     B, N1, G1, C0);
    k_stdsum<<<256, 256, 0, stream>>>(xyz,    lcx1, ki1, acc + 2, B, N1, G1, 3);
    k_finalize<<<1, 64, 0, stream>>>(acc, inv1, (double)B*G1*KNB*C0, (double)B*G1*KNB*3);
    {
        size_t shf = (size_t)(KNB*7 + KNB*3 + KNB + KNB*C0) * 4;
        k_feature<<<B*G1, 256, shf, stream>>>(xyz, feats1, lcx1, lcf1, ki1, B0, inv1, pooled1,
                                              B, N1, G1, C0);
    }
    k_bnstats<<<Co1, 256, 0, stream>>>(pooled1, stats1, B, Co1, G1);
    k_bn_gelu<<<(B*Co1*G1 + 255)/256, 256, 0, stream>>>(pooled1, stats1, g0, be0, feats2,
                                                        B, Co1, G1, 1);

    // ---- stage 2 (xyz = lcx1, feats = feats2) ----
    k_fps<<<B, 1024, (size_t)(3*N2 + 80)*4, stream>>>(lcx1, fi2, B, N2, G2);
    k_gather<<<(B*G2*(C1+3) + 255)/256, 256, 0, stream>>>(lcx1, feats2, fi2, lcx2, lcf2, B, N2, G2, C1);
    k_knn<<<B*G2, 256, (size_t)(N2 + 32)*4, stream>>>(lcx1, lcx2, ki2, B, N2, G2);
    k_stdsum<<<512, 256, 0, stream>>>(feats2, lcf2, ki2, acc + 4, B, N2, G2, C1);
    k_stdsum<<<256, 256, 0, stream>>>(lcx1,   lcx2, ki2, acc + 6, B, N2, G2, 3);
    k_finalize<<<1, 64, 0, stream>>>(acc + 4, inv2, (double)B*G2*KNB*C1, (double)B*G2*KNB*3);
    {
        size_t shf = (size_t)(KNB*7 + KNB*3 + KNB + KNB*C1) * 4;
        k_feature<<<B*G2, 256, shf, stream>>>(lcx1, feats2, lcx2, lcf2, ki2, B1, inv2, pooled2,
                                              B, N2, G2, C1);
    }
    k_bnstats<<<Co2, 256, 0, stream>>>(pooled2, stats2, B, Co2, G2);
    k_bn_gelu<<<(B*Co2*G2 + 255)/256, 256, 0, stream>>>(pooled2, stats2, g1, be1, out,
                                                        B, Co2, G2, 0);
}

// Round 2
// 3086.650 us; speedup vs baseline: 2.9384x; 2.9384x over previous
//
#include <hip/hip_runtime.h>
#include <math.h>

#define KNB 24

// ---------------------------------------------------------------- utilities
__global__ void k_zero(double* acc) {
    if (threadIdx.x < 8) acc[threadIdx.x] = 0.0;
}

// x [B,C,N] -> feats [B,N,C]
__global__ void k_transpose(const float* __restrict__ x, float* __restrict__ feats,
                            int B, int C, int N) {
    int idx = blockIdx.x * blockDim.x + threadIdx.x;
    int tot = B * C * N;
    if (idx >= tot) return;
    int n = idx % N; int t = idx / N; int c = t % C; int b = t / C;
    feats[((size_t)b * N + n) * C + c] = x[idx];
}

// ---------------------------------------------------------------- FPS (register-resident, 1 barrier/iter)
// one workgroup (256 threads) per batch. Thread t owns points [t*NPT, (t+1)*NPT).
// Per iter: reg update + f32-only butterfly max + ballot index recovery +
// packed-u64 cross-wave exchange (parity double-buffered) -> ONE __syncthreads.
template<int NPT>
__global__ __launch_bounds__(256) void k_fps_t(const float* __restrict__ xyz,
                                               int* __restrict__ fi,
                                               int N, int M) {
#pragma clang fp contract(off)
    const int b = blockIdx.x;
    const int tid = threadIdx.x;
    const int lane = tid & 63;
    const int wid = tid >> 6;              // 0..3
    extern __shared__ unsigned long long smem_u64[];
    unsigned long long* keys = smem_u64;   // [2][4] parity-double-buffered
    float* px = (float*)(smem_u64 + 8);
    float* py = px + N;
    float* pz = py + N;

    const float* p = xyz + (size_t)b * N * 3;
    for (int i = tid; i < N; i += 256) { px[i] = p[i*3]; py[i] = p[i*3+1]; pz[i] = p[i*3+2]; }
    __syncthreads();

    const int base = tid * NPT;
    float rx[NPT], ry[NPT], rz[NPT], dist[NPT];
#pragma unroll
    for (int j = 0; j < NPT; ++j) {
        rx[j] = px[base + j]; ry[j] = py[base + j]; rz[j] = pz[base + j];
        dist[j] = 1e10f;
    }

    int far = 0;
    for (int it = 0; it < M; ++it) {
        if (tid == 0) fi[b * M + it] = far;          // record carry BEFORE update
        float cx = px[far], cy = py[far], cz = pz[far];
        float bv = -1.0f; int bi = 0;
#pragma unroll
        for (int j = 0; j < NPT; ++j) {
            float dx = rx[j] - cx, dy = ry[j] - cy, dz = rz[j] - cz;
            float d = (dx*dx + dy*dy) + dz*dz;       // ((d0+d1)+d2), no fma
            float dd = fminf(dist[j], d);
            dist[j] = dd;
            if (dd > bv) { bv = dd; bi = base + j; } // ascending j -> first-max kept
        }
        float lbv = bv;
        // value-only butterfly max across the wave
#pragma unroll
        for (int off = 32; off > 0; off >>= 1) {
            float ov = __shfl_xor(bv, off);
            bv = fmaxf(bv, ov);
        }
        // recover index: lowest lane holding the max = smallest global index
        unsigned long long mask = __ballot(lbv == bv);
        int src = __builtin_ctzll(mask);
        int wbi = __shfl(bi, src);
        // pack: max key -> max dist, tie -> min index
        unsigned long long key =
            ((unsigned long long)__float_as_uint(bv) << 32) | (unsigned)(~wbi);
        if (lane == 0) keys[(it & 1) * 4 + wid] = key;
        __syncthreads();
        unsigned long long k0 = keys[(it & 1) * 4 + 0];
        unsigned long long k1 = keys[(it & 1) * 4 + 1];
        unsigned long long k2 = keys[(it & 1) * 4 + 2];
        unsigned long long k3 = keys[(it & 1) * 4 + 3];
        if (k1 > k0) k0 = k1;
        if (k2 > k0) k0 = k2;
        if (k3 > k0) k0 = k3;
        far = (int)(~(unsigned)k0);
    }
}

// ---------------------------------------------------------------- gather centers
__global__ void k_gather(const float* __restrict__ xyz, const float* __restrict__ feats,
                         const int* __restrict__ fi, float* __restrict__ lc_xyz,
                         float* __restrict__ lc_x, int B, int N, int G, int C) {
    int i = blockIdx.x * blockDim.x + threadIdx.x;
    int tot = B * G * (C + 3);
    if (i >= tot) return;
    int c = i % (C + 3); int bg = i / (C + 3);
    int b = bg / G;
    int idx = fi[bg];
    if (c < 3) lc_xyz[(size_t)bg * 3 + c] = xyz[((size_t)b * N + idx) * 3 + c];
    else       lc_x[(size_t)bg * C + (c - 3)] = feats[((size_t)b * N + idx) * C + (c - 3)];
}

// ---------------------------------------------------------------- kNN (24 smallest, ties->lower idx)
__global__ __launch_bounds__(256) void k_knn(const float* __restrict__ xyz,
                                             const float* __restrict__ lc_xyz,
                                             int* __restrict__ ki, int B, int N, int G) {
#pragma clang fp contract(off)
    int bg = blockIdx.x; int b = bg / G;
    extern __shared__ float sd[];
    float* rv = sd + N; int* ri = (int*)(rv + 8);
    const float* p = xyz + (size_t)b * N * 3;
    float cx = lc_xyz[(size_t)bg*3], cy = lc_xyz[(size_t)bg*3+1], cz = lc_xyz[(size_t)bg*3+2];
    float cc = (cx*cx + cy*cy) + cz*cz;
    for (int i = threadIdx.x; i < N; i += blockDim.x) {
        float x0 = p[i*3], x1 = p[i*3+1], x2 = p[i*3+2];
        float xx = (x0*x0 + x1*x1) + x2*x2;
        float dt = (cx*x0 + cy*x1) + cz*x2;
        sd[i] = (cc - 2.0f*dt) + xx;          // (cc - 2dot) + xx, matches ref assoc
    }
    __syncthreads();
    for (int kk = 0; kk < KNB; ++kk) {
        float bv = 1e30f; int bi = N;
        for (int i = threadIdx.x; i < N; i += blockDim.x) {
            float v = sd[i];
            if (v < bv) { bv = v; bi = i; }   // i increasing -> first-min kept
        }
        for (int off = 32; off > 0; off >>= 1) {
            float ov = __shfl_down(bv, off); int oi = __shfl_down(bi, off);
            if (ov < bv || (ov == bv && oi < bi)) { bv = ov; bi = oi; }
        }
        int wid = threadIdx.x >> 6;
        if ((threadIdx.x & 63) == 0) { rv[wid] = bv; ri[wid] = bi; }
        __syncthreads();
        if (threadIdx.x == 0) {
            int nw = blockDim.x >> 6;
            float v = rv[0]; int ii = ri[0];
            for (int w = 1; w < nw; ++w) {
                if (rv[w] < v || (rv[w] == v && ri[w] < ii)) { v = rv[w]; ii = ri[w]; }
            }
            ki[(size_t)bg * KNB + kk] = ii;
            sd[ii] = 1e30f;
        }
        __syncthreads();
    }
}

// ---------------------------------------------------------------- global std reduction (sum, sumsq)
__global__ void k_stdsum(const float* __restrict__ feats, const float* __restrict__ lc,
                         const int* __restrict__ ki, double* __restrict__ acc,
                         int B, int N, int G, int C) {
    size_t tot = (size_t)B * G * KNB * C;
    double s = 0.0, s2 = 0.0;
    size_t stride = (size_t)gridDim.x * blockDim.x;
    for (size_t i = (size_t)blockIdx.x * blockDim.x + threadIdx.x; i < tot; i += stride) {
        int c = (int)(i % C); size_t t = i / C; int k = (int)(t % KNB); size_t bg = t / KNB;
        int b = (int)(bg / G);
        int idx = ki[bg * KNB + k];
        float d = feats[((size_t)b * N + idx) * C + c] - lc[bg * C + c];
        s += (double)d; s2 += (double)d * (double)d;
    }
    for (int off = 32; off > 0; off >>= 1) { s += __shfl_down(s, off); s2 += __shfl_down(s2, off); }
    if ((threadIdx.x & 63) == 0) { atomicAdd(acc, s); atomicAdd(acc + 1, s2); }
}

__global__ void k_finalize(const double* __restrict__ acc, float* __restrict__ inv,
                           double nx, double nz) {
    if (threadIdx.x == 0) {
        double vx = (acc[1] - acc[0] * acc[0] / nx) / (nx - 1.0);
        float sx = sqrtf((float)vx);
        inv[0] = 1.0f / (sx + 1e-5f);
        double vz = (acc[3] - acc[2] * acc[2] / nz) / (nz - 1.0);
        float sz = sqrtf((float)vz);
        inv[1] = 1.0f / (sz + 1e-5f);
    }
}

// ---------------------------------------------------------------- LGA feature + pool (one wg per (b,g))
__global__ __launch_bounds__(256) void k_feature(
    const float* __restrict__ xyz, const float* __restrict__ feats,
    const float* __restrict__ lc_xyz, const float* __restrict__ lc_x,
    const int* __restrict__ ki, const float* __restrict__ Bmat,
    const float* __restrict__ inv, float* __restrict__ pooled,
    int B, int N, int G, int C)
{
    int bg = blockIdx.x; int b = bg / G; int g = bg % G;
    int tid = threadIdx.x;
    int C2 = C >> 1;
    int Cout = 2 * C;
    int F = C / 3;                         // tr_embed F = (2C)/(2*3)
    extern __shared__ float sm[];
    float* t7    = sm;                     // [24][7]
    float* sxyzn = t7 + KNB * 7;           // [24][3]
    int*   kidx  = (int*)(sxyzn + KNB * 3);// [24]
    float* semb  = (float*)(kidx + KNB);   // [24][C]

    float invx = inv[0], invz = inv[1];
    float l0 = lc_xyz[(size_t)bg*3], l1 = lc_xyz[(size_t)bg*3+1], l2 = lc_xyz[(size_t)bg*3+2];

    if (tid < KNB) {
        int idx = ki[(size_t)bg * KNB + tid];
        kidx[tid] = idx;
        const float* q = xyz + ((size_t)b * N + idx) * 3;
        float a0 = (q[0]-l0)*invz, a1 = (q[1]-l1)*invz, a2 = (q[2]-l2)*invz;
        float c0 = a1*l2 - a2*l1;          // cross(normed knn_xyz, raw lc_xyz)
        float c1 = a2*l0 - a0*l2;
        float c2 = a0*l1 - a1*l0;
        float dt = (a0*l0 + a1*l1) + a2*l2;
        float* tp = t7 + tid * 7;
        tp[0]=a0; tp[1]=a1; tp[2]=a2; tp[3]=c0; tp[4]=c1; tp[5]=c2; tp[6]=dt;
        sxyzn[tid*3]=a0; sxyzn[tid*3+1]=a1; sxyzn[tid*3+2]=a2;
    }
    __syncthreads();
    const float TWO_PI = 6.2831854820251465f;
    // fourier embedding: emb[k][c] = sin(proj)^5 / cos(proj)^5
    for (int i = tid; i < KNB * C2; i += blockDim.x) {
        int k = i / C2, m2 = i % C2;
        const float* tp = t7 + k * 7;
        float s = 0.0f;
        for (int j = 0; j < 7; ++j) s += tp[j] * Bmat[j * C2 + m2];
        float pr = TWO_PI * s;
        float sn = sinf(pr), cs = cosf(pr);
        float sn2 = sn*sn, cs2 = cs*cs;
        semb[k*C + m2]      = sn2*sn2*sn;
        semb[k*C + C2 + m2] = cs2*cs2*cs;
    }
    __syncthreads();
    // per output channel m: w = (knn_x_w + pe)*pe ; pooled = 2*mean_K(w)  (k_anp cancels)
    for (int m = tid; m < Cout; m += blockDim.x) {
        int c3 = m / (2 * F);
        int r  = m % (2 * F);
        int f  = r >> 1;
        int trig = r & 1;
        float de = powf(100.0f, (float)f / (float)F);
        float lv = (c3 == 0) ? l0 : ((c3 == 1) ? l1 : l2);
        float a2v = (1000.0f * lv) / de;
        float pe2 = trig ? cosf(a2v) : sinf(a2v);
        float lfm = (m < C) ? lc_x[(size_t)bg * C + m] : 0.0f;
        float acc = 0.0f;
        for (int k = 0; k < KNB; ++k) {
            float v;
            if (m < C) {
                v = (feats[((size_t)b * N + kidx[k]) * C + m] - lfm) * invx;
            } else {
                v = semb[k * C + (m - C)];
            }
            float a1v = (1000.0f * sxyzn[k*3 + c3]) / de;
            float pe1 = trig ? cosf(a1v) : sinf(a1v);
            float pe = pe1 + pe2;
            acc += (v + pe) * pe;
        }
        float mean = acc / 24.0f;
        pooled[((size_t)b * Cout + m) * G + g] = 2.0f * mean;   // k_anp + mean = 2*mean
    }
}

// ---------------------------------------------------------------- BatchNorm stats (train mode, biased var)
__global__ __launch_bounds__(256) void k_bnstats(const float* __restrict__ pooled,
                                                 float* __restrict__ stats,
                                                 int B, int Cout, int G) {
    int m = blockIdx.x;
    double s = 0.0, s2 = 0.0;
    for (int i = threadIdx.x; i < B * G; i += blockDim.x) {
        int b = i / G, g = i % G;
        float v = pooled[((size_t)b * Cout + m) * G + g];
        s += (double)v; s2 += (double)v * (double)v;
    }
    for (int off = 32; off > 0; off >>= 1) { s += __shfl_down(s, off); s2 += __shfl_down(s2, off); }
    __shared__ double sw[8], sw2[8];
    int wid = threadIdx.x >> 6;
    if ((threadIdx.x & 63) == 0) { sw[wid] = s; sw2[wid] = s2; }
    __syncthreads();
    if (threadIdx.x == 0) {
        int nw = blockDim.x >> 6;
        double ts = 0.0, ts2 = 0.0;
        for (int w = 0; w < nw; ++w) { ts += sw[w]; ts2 += sw2[w]; }
        double n = (double)(B * G);
        double mean = ts / n;
        double var = ts2 / n - mean * mean;
        stats[2*m]   = (float)mean;
        stats[2*m+1] = (float)var;
    }
}

// BN apply + exact GELU; transposed=1 writes [B,G,Cout] (feats layout for next stage)
__global__ void k_bn_gelu(const float* __restrict__ pooled, const float* __restrict__ stats,
                          const float* __restrict__ gamma, const float* __restrict__ beta,
                          float* __restrict__ out, int B, int Cout, int G, int transposed) {
    int i = blockIdx.x * blockDim.x + threadIdx.x;
    int tot = B * Cout * G;
    if (i >= tot) return;
    int g = i % G; int t = i / G; int m = t % Cout; int b = t / Cout;
    float v = pooled[i];
    float mean = stats[2*m], var = stats[2*m+1];
    float y = (v - mean) / sqrtf(var + 1e-5f) * gamma[m] + beta[m];
    float ge = 0.5f * y * (1.0f + erff(y / 1.4142135381698608f));
    if (transposed) out[((size_t)b * G + g) * Cout + m] = ge;
    else            out[i] = ge;
}

// ---------------------------------------------------------------- launch
extern "C" void kernel_launch(void* const* d_in, const int* in_sizes, int n_in,
                              void* d_out, int out_size, void* d_ws, size_t ws_size,
                              hipStream_t stream) {
    const int B = 4, N1 = 4096, C0 = 72, G1 = 2048, Co1 = 144;
    const int N2 = 2048, C1 = 144, G2 = 1024, Co2 = 288;

    const float* xyz = (const float*)d_in[0];
    const float* x0  = (const float*)d_in[1];
    const float* B0  = (const float*)d_in[2];
    const float* B1  = (const float*)d_in[3];
    const float* g0  = (const float*)d_in[4];
    const float* be0 = (const float*)d_in[5];
    const float* g1  = (const float*)d_in[6];
    const float* be1 = (const float*)d_in[7];
    float* out = (float*)d_out;

    char* wp = (char*)d_ws;
    size_t off = 0;
    auto A = [&](size_t bytes) -> void* {
        void* p = wp + off;
        off += (bytes + 255) & ~(size_t)255;
        return p;
    };
    float* feats1  = (float*)A((size_t)B*N1*C0*4);
    int*   fi1     = (int*)  A((size_t)B*G1*4);
    float* lcx1    = (float*)A((size_t)B*G1*3*4);
    float* lcf1    = (float*)A((size_t)B*G1*C0*4);
    int*   ki1     = (int*)  A((size_t)B*G1*KNB*4);
    double* acc    = (double*)A(8*8);
    float* inv1    = (float*)A(2*4);
    float* inv2    = (float*)A(2*4);
    float* pooled1 = (float*)A((size_t)B*Co1*G1*4);
    float* stats1  = (float*)A((size_t)Co1*2*4);
    float* feats2  = (float*)A((size_t)B*N2*C1*4);
    float* lcx2    = (float*)A((size_t)B*G2*3*4);
    float* stats2  = (float*)A((size_t)Co2*2*4);
    // aliases (lifetimes disjoint, sizes checked: equal or smaller)
    int*   fi2     = fi1;
    float* lcf2    = lcf1;     // B*G2*C1 == B*G1*C0
    int*   ki2     = ki1;
    float* pooled2 = feats1;   // B*Co2*G2 == B*N1*C0

    k_zero<<<1, 64, 0, stream>>>(acc);
    k_transpose<<<(B*C0*N1 + 255)/256, 256, 0, stream>>>(x0, feats1, B, C0, N1);

    // ---- stage 1 ----
    k_fps_t<16><<<B, 256, (size_t)(64 + 3*N1*4), stream>>>(xyz, fi1, N1, G1);
    k_gather<<<(B*G1*(C0+3) + 255)/256, 256, 0, stream>>>(xyz, feats1, fi1, lcx1, lcf1, B, N1, G1, C0);
    k_knn<<<B*G1, 256, (size_t)(N1 + 32)*4, stream>>>(xyz, lcx1, ki1, B, N1, G1);
    k_stdsum<<<512, 256, 0, stream>>>(feats1, lcf1, ki1, acc,     B, N1, G1, C0);
    k_stdsum<<<256, 256, 0, stream>>>(xyz,    lcx1, ki1, acc + 2, B, N1, G1, 3);
    k_finalize<<<1, 64, 0, stream>>>(acc, inv1, (double)B*G1*KNB*C0, (double)B*G1*KNB*3);
    {
        size_t shf = (size_t)(KNB*7 + KNB*3 + KNB + KNB*C0) * 4;
        k_feature<<<B*G1, 256, shf, stream>>>(xyz, feats1, lcx1, lcf1, ki1, B0, inv1, pooled1,
                                              B, N1, G1, C0);
    }
    k_bnstats<<<Co1, 256, 0, stream>>>(pooled1, stats1, B, Co1, G1);
    k_bn_gelu<<<(B*Co1*G1 + 255)/256, 256, 0, stream>>>(pooled1, stats1, g0, be0, feats2,
                                                        B, Co1, G1, 1);

    // ---- stage 2 (xyz = lcx1, feats = feats2) ----
    k_fps_t<8><<<B, 256, (size_t)(64 + 3*N2*4), stream>>>(lcx1, fi2, N2, G2);
    k_gather<<<(B*G2*(C1+3) + 255)/256, 256, 0, stream>>>(lcx1, feats2, fi2, lcx2, lcf2, B, N2, G2, C1);
    k_knn<<<B*G2, 256, (size_t)(N2 + 32)*4, stream>>>(lcx1, lcx2, ki2, B, N2, G2);
    k_stdsum<<<512, 256, 0, stream>>>(feats2, lcf2, ki2, acc + 4, B, N2, G2, C1);
    k_stdsum<<<256, 256, 0, stream>>>(lcx1,   lcx2, ki2, acc + 6, B, N2, G2, 3);
    k_finalize<<<1, 64, 0, stream>>>(acc + 4, inv2, (double)B*G2*KNB*C1, (double)B*G2*KNB*3);
    {
        size_t shf = (size_t)(KNB*7 + KNB*3 + KNB + KNB*C1) * 4;
        k_feature<<<B*G2, 256, shf, stream>>>(lcx1, feats2, lcx2, lcf2, ki2, B1, inv2, pooled2,
                                              B, N2, G2, C1);
    }
    k_bnstats<<<Co2, 256, 0, stream>>>(pooled2, stats2, B, Co2, G2);
    k_bn_gelu<<<(B*Co2*G2 + 255)/256, 256, 0, stream>>>(pooled2, stats2, g1, be1, out,
                                                        B, Co2, G2, 0);
}